// Round 1
// baseline (439.395 us; speedup 1.0000x reference)
//
#include <hip/hip_runtime.h>
#include <hip/hip_bf16.h>

#define NN 50000
#define NE 800000
#define DF 128

typedef __bf16 bf16x8 __attribute__((ext_vector_type(8)));
typedef float f32x4 __attribute__((ext_vector_type(4)));

__device__ __forceinline__ unsigned short f32_to_bf16_rne(float f) {
    unsigned int u = __float_as_uint(f);
    u += 0x7fffu + ((u >> 16) & 1u);
    return (unsigned short)(u >> 16);
}

// ---------------- graph build ----------------
__global__ __launch_bounds__(256) void k_degree(const int* __restrict__ dst, int* __restrict__ deg, int e) {
    int i = blockIdx.x * 256 + threadIdx.x;
    if (i < e) atomicAdd(&deg[dst[i]], 1);
}

__global__ __launch_bounds__(256) void k_scan1(const int* __restrict__ deg, int* __restrict__ part, int n) {
    __shared__ int sm[256];
    int i = blockIdx.x * 256 + threadIdx.x;
    int v = (i < n) ? deg[i] : 0;
    sm[threadIdx.x] = v;
    __syncthreads();
    for (int s = 128; s > 0; s >>= 1) {
        if (threadIdx.x < s) sm[threadIdx.x] += sm[threadIdx.x + s];
        __syncthreads();
    }
    if (threadIdx.x == 0) part[blockIdx.x] = sm[0];
}

__global__ __launch_bounds__(256) void k_scan2(int* __restrict__ part, int nblk, int* __restrict__ row_ptr,
                                               int n, int etot) {
    __shared__ int sm[256];
    int t = threadIdx.x;
    int v = (t < nblk) ? part[t] : 0;
    sm[t] = v;
    __syncthreads();
    for (int off = 1; off < 256; off <<= 1) {
        int x = (t >= off) ? sm[t - off] : 0;
        __syncthreads();
        sm[t] += x;
        __syncthreads();
    }
    if (t < nblk) part[t] = sm[t] - v;  // exclusive block offsets
    if (t == 0) row_ptr[n] = etot;
}

__global__ __launch_bounds__(256) void k_scan3(const int* __restrict__ deg, const int* __restrict__ part,
                                               int* __restrict__ row_ptr, int* __restrict__ cursor,
                                               float* __restrict__ inv_deg, int n) {
    __shared__ int sm[256];
    int i = blockIdx.x * 256 + threadIdx.x;
    int t = threadIdx.x;
    int v = (i < n) ? deg[i] : 0;
    sm[t] = v;
    __syncthreads();
    for (int off = 1; off < 256; off <<= 1) {
        int x = (t >= off) ? sm[t - off] : 0;
        __syncthreads();
        sm[t] += x;
        __syncthreads();
    }
    if (i < n) {
        int excl = sm[t] - v + part[blockIdx.x];
        row_ptr[i] = excl;
        cursor[i] = excl;
        inv_deg[i] = 1.0f / (float)((v > 1) ? v : 1);
    }
}

__global__ __launch_bounds__(256) void k_scatter(const int* __restrict__ src, const int* __restrict__ dst,
                                                 int* __restrict__ cursor, int* __restrict__ col, int e) {
    int i = blockIdx.x * 256 + threadIdx.x;
    if (i < e) {
        int p = atomicAdd(&cursor[dst[i]], 1);
        col[p] = src[i];
    }
}

// ---------------- dtype convert (n must be %4) ----------------
__global__ __launch_bounds__(256) void k_f2b(const float* __restrict__ f, unsigned short* __restrict__ o, int n) {
    int i = (blockIdx.x * 256 + threadIdx.x) * 4;
    if (i < n) {
        float4 v = *reinterpret_cast<const float4*>(f + i);
        ushort4 r;
        r.x = f32_to_bf16_rne(v.x);
        r.y = f32_to_bf16_rne(v.y);
        r.z = f32_to_bf16_rne(v.z);
        r.w = f32_to_bf16_rne(v.w);
        *reinterpret_cast<ushort4*>(o + i) = r;
    }
}

// ---------------- aggregation: one wave per node, lane owns 2 feats ----------------
__global__ __launch_bounds__(256) void k_agg(const unsigned short* __restrict__ H,
                                             const int* __restrict__ row_ptr, const int* __restrict__ col,
                                             const float* __restrict__ inv_deg,
                                             unsigned short* __restrict__ Agg, int n) {
    int wid = threadIdx.x >> 6;
    int lane = threadIdx.x & 63;
    int node = blockIdx.x * 4 + wid;
    if (node >= n) return;
    int s = row_ptr[node], e = row_ptr[node + 1];
    float a0 = 0.f, a1 = 0.f;
    int off = lane * 2;
    for (int j = s; j < e; ++j) {
        int c = col[j];
        unsigned int u = *reinterpret_cast<const unsigned int*>(H + (size_t)c * DF + off);
        a0 += __uint_as_float(u << 16);
        a1 += __uint_as_float(u & 0xffff0000u);
    }
    float iv = inv_deg[node];
    a0 *= iv; a1 *= iv;
    unsigned int r = (unsigned int)f32_to_bf16_rne(a0) | ((unsigned int)f32_to_bf16_rne(a1) << 16);
    *reinterpret_cast<unsigned int*>(Agg + (size_t)node * DF + off) = r;
}

// ---------------- fused GEMM: out = relu(Hb@Ws^T + Ab@Wn^T + bias) ----------------
// BM=64 rows/block, 4 waves, wave w owns output cols [32w,32w+32). K=256 (two phases).
__global__ __launch_bounds__(256) void k_gemm(const unsigned short* __restrict__ Hb,
                                              const unsigned short* __restrict__ Ab,
                                              const unsigned short* __restrict__ Wb,  // Ws | Wn (bf16)
                                              const float* __restrict__ bias,
                                              unsigned short* __restrict__ Hout,  // may alias Hb (or null)
                                              float* __restrict__ Fout,           // f32 out (or null)
                                              int n) {
    int brow = blockIdx.x * 64;
    int lane = threadIdx.x & 63;
    int wid = threadIdx.x >> 6;
    int l15 = lane & 15;
    int lk = (lane >> 4) * 8;
    int colb = wid * 32;

    f32x4 zero = {0.f, 0.f, 0.f, 0.f};
    f32x4 acc[4][2];
#pragma unroll
    for (int m = 0; m < 4; ++m) {
        acc[m][0] = zero;
        acc[m][1] = zero;
    }

#pragma unroll
    for (int ph = 0; ph < 2; ++ph) {
        const unsigned short* Ap = ph ? Ab : Hb;
        const unsigned short* Wp = Wb + ph * (DF * DF);
#pragma unroll
        for (int ks = 0; ks < 4; ++ks) {
            int kb = ks * 32 + lk;
            bf16x8 bfr0 = *reinterpret_cast<const bf16x8*>(Wp + (colb + l15) * DF + kb);
            bf16x8 bfr1 = *reinterpret_cast<const bf16x8*>(Wp + (colb + 16 + l15) * DF + kb);
#pragma unroll
            for (int m = 0; m < 4; ++m) {
                int r = brow + m * 16 + l15;
                if (r >= n) r = n - 1;
                bf16x8 afr = *reinterpret_cast<const bf16x8*>(Ap + (size_t)r * DF + kb);
                acc[m][0] = __builtin_amdgcn_mfma_f32_16x16x32_bf16(afr, bfr0, acc[m][0], 0, 0, 0);
                acc[m][1] = __builtin_amdgcn_mfma_f32_16x16x32_bf16(afr, bfr1, acc[m][1], 0, 0, 0);
            }
        }
    }

    __syncthreads();  // in-place safety: all waves' A reads complete before any store

    int rb = (lane >> 4) * 4;
#pragma unroll
    for (int q = 0; q < 2; ++q) {
        int o = colb + q * 16 + l15;
        float bv = bias[o];
#pragma unroll
        for (int m = 0; m < 4; ++m) {
#pragma unroll
            for (int j = 0; j < 4; ++j) {
                int r = brow + m * 16 + rb + j;
                if (r < n) {
                    float v = fmaxf(acc[m][q][j] + bv, 0.f);
                    if (Fout) Fout[(size_t)r * DF + o] = v;
                    else Hout[(size_t)r * DF + o] = f32_to_bf16_rne(v);
                }
            }
        }
    }
}

extern "C" void kernel_launch(void* const* d_in, const int* in_sizes, int n_in,
                              void* d_out, int out_size, void* d_ws, size_t ws_size,
                              hipStream_t stream) {
    const float* feats = (const float*)d_in[0];
    const int* src = (const int*)d_in[1];
    const int* dst = (const int*)d_in[2];
    const float* Wf[6] = {(const float*)d_in[3], (const float*)d_in[4],
                          (const float*)d_in[6], (const float*)d_in[7],
                          (const float*)d_in[9], (const float*)d_in[10]};
    const float* bias[3] = {(const float*)d_in[5], (const float*)d_in[8], (const float*)d_in[11]};

    char* ws = (char*)d_ws;
    unsigned short* h_bf = (unsigned short*)(ws);                 // 12,800,000 B
    unsigned short* agg_bf = (unsigned short*)(ws + 12800000);    // 12,800,000 B
    unsigned short* Wb = (unsigned short*)(ws + 25600000);        // 196,608 B
    int* deg = (int*)(ws + 25796608);                             // 200,000 B
    int* row_ptr = (int*)(ws + 25996608);                         // 200,004 B
    int* cursor = (int*)(ws + 26196624);                          // 200,000 B
    float* inv_deg = (float*)(ws + 26396624);                     // 200,000 B
    int* col = (int*)(ws + 26596624);                             // 3,200,000 B
    int* part = (int*)(ws + 29796624);                            // 1,024 B

    hipMemsetAsync(deg, 0, NN * sizeof(int), stream);
    k_degree<<<(NE + 255) / 256, 256, 0, stream>>>(dst, deg, NE);
    int nblk = (NN + 255) / 256;  // 196
    k_scan1<<<nblk, 256, 0, stream>>>(deg, part, NN);
    k_scan2<<<1, 256, 0, stream>>>(part, nblk, row_ptr, NN, NE);
    k_scan3<<<nblk, 256, 0, stream>>>(deg, part, row_ptr, cursor, inv_deg, NN);
    k_scatter<<<(NE + 255) / 256, 256, 0, stream>>>(src, dst, cursor, col, NE);

    k_f2b<<<(NN * DF / 4 + 255) / 256, 256, 0, stream>>>(feats, h_bf, NN * DF);
    for (int i = 0; i < 6; ++i)
        k_f2b<<<16, 256, 0, stream>>>(Wf[i], Wb + i * DF * DF, DF * DF);

    int gblk = (NN + 63) / 64;  // 782
    for (int l = 0; l < 3; ++l) {
        k_agg<<<(NN + 3) / 4, 256, 0, stream>>>(h_bf, row_ptr, col, inv_deg, agg_bf, NN);
        const unsigned short* Wl = Wb + l * 2 * DF * DF;
        if (l < 2)
            k_gemm<<<gblk, 256, 0, stream>>>(h_bf, agg_bf, Wl, bias[l], h_bf, nullptr, NN);
        else
            k_gemm<<<gblk, 256, 0, stream>>>(h_bf, agg_bf, Wl, bias[l], nullptr, (float*)d_out, NN);
    }
}

// Round 2
// 313.256 us; speedup vs baseline: 1.4027x; 1.4027x over previous
//
#include <hip/hip_runtime.h>
#include <hip/hip_bf16.h>

#define NN 50000
#define NE 800000
#define DF 128

typedef __bf16 bf16x8 __attribute__((ext_vector_type(8)));
typedef float f32x4 __attribute__((ext_vector_type(4)));

__device__ __forceinline__ unsigned short f32_to_bf16_rne(float f) {
    unsigned int u = __float_as_uint(f);
    u += 0x7fffu + ((u >> 16) & 1u);
    return (unsigned short)(u >> 16);
}

__device__ __forceinline__ unsigned int pack_bf16x2(float lo, float hi) {
    return (unsigned int)f32_to_bf16_rne(lo) | ((unsigned int)f32_to_bf16_rne(hi) << 16);
}

// ---------------- graph build ----------------
__global__ __launch_bounds__(256) void k_degree(const int* __restrict__ dst, int* __restrict__ deg, int e) {
    int i = blockIdx.x * 256 + threadIdx.x;
    if (i < e) atomicAdd(&deg[dst[i]], 1);
}

__global__ __launch_bounds__(256) void k_scan1(const int* __restrict__ deg, int* __restrict__ part, int n) {
    __shared__ int sm[256];
    int i = blockIdx.x * 256 + threadIdx.x;
    int v = (i < n) ? deg[i] : 0;
    sm[threadIdx.x] = v;
    __syncthreads();
    for (int s = 128; s > 0; s >>= 1) {
        if (threadIdx.x < s) sm[threadIdx.x] += sm[threadIdx.x + s];
        __syncthreads();
    }
    if (threadIdx.x == 0) part[blockIdx.x] = sm[0];
}

__global__ __launch_bounds__(256) void k_scan2(int* __restrict__ part, int nblk, int* __restrict__ row_ptr,
                                               int n, int etot) {
    __shared__ int sm[256];
    int t = threadIdx.x;
    int v = (t < nblk) ? part[t] : 0;
    sm[t] = v;
    __syncthreads();
    for (int off = 1; off < 256; off <<= 1) {
        int x = (t >= off) ? sm[t - off] : 0;
        __syncthreads();
        sm[t] += x;
        __syncthreads();
    }
    if (t < nblk) part[t] = sm[t] - v;  // exclusive block offsets
    if (t == 0) row_ptr[n] = etot;
}

__global__ __launch_bounds__(256) void k_scan3(const int* __restrict__ deg, const int* __restrict__ part,
                                               int* __restrict__ row_ptr, int* __restrict__ cursor,
                                               float* __restrict__ inv_deg, int n) {
    __shared__ int sm[256];
    int i = blockIdx.x * 256 + threadIdx.x;
    int t = threadIdx.x;
    int v = (i < n) ? deg[i] : 0;
    sm[t] = v;
    __syncthreads();
    for (int off = 1; off < 256; off <<= 1) {
        int x = (t >= off) ? sm[t - off] : 0;
        __syncthreads();
        sm[t] += x;
        __syncthreads();
    }
    if (i < n) {
        int excl = sm[t] - v + part[blockIdx.x];
        row_ptr[i] = excl;
        cursor[i] = excl;
        inv_deg[i] = 1.0f / (float)((v > 1) ? v : 1);
    }
}

__global__ __launch_bounds__(256) void k_scatter(const int* __restrict__ src, const int* __restrict__ dst,
                                                 int* __restrict__ cursor, int* __restrict__ col, int e) {
    int i = blockIdx.x * 256 + threadIdx.x;
    if (i < e) {
        int p = atomicAdd(&cursor[dst[i]], 1);
        col[p] = src[i];
    }
}

// ---------------- dtype convert (n must be %4) ----------------
__global__ __launch_bounds__(256) void k_f2b(const float* __restrict__ f, unsigned short* __restrict__ o, int n) {
    int i = (blockIdx.x * 256 + threadIdx.x) * 4;
    if (i < n) {
        float4 v = *reinterpret_cast<const float4*>(f + i);
        ushort4 r;
        r.x = f32_to_bf16_rne(v.x);
        r.y = f32_to_bf16_rne(v.y);
        r.z = f32_to_bf16_rne(v.z);
        r.w = f32_to_bf16_rne(v.w);
        *reinterpret_cast<ushort4*>(o + i) = r;
    }
}

// ---------------- aggregation v2 ----------------
// One wave per node. 4 groups of 16 lanes; group g handles neighbor j+g, lane
// owns 8 feats (16B dwordx4 load). Unroll x2 -> 8 independent row-gathers in
// flight per wave. Final: 2-stage shfl_xor cross-group reduce, group 0 writes.
__global__ __launch_bounds__(256) void k_agg(const unsigned short* __restrict__ H,
                                             const int* __restrict__ row_ptr, const int* __restrict__ col,
                                             const float* __restrict__ inv_deg,
                                             unsigned short* __restrict__ Agg, int n) {
    int wid = threadIdx.x >> 6;
    int lane = threadIdx.x & 63;
    int node = blockIdx.x * 4 + wid;
    if (node >= n) return;
    int s = row_ptr[node], e = row_ptr[node + 1];
    int g = lane >> 4;
    int l = lane & 15;
    int off = l * 8;  // 8 bf16 per lane

    float a[8];
#pragma unroll
    for (int k = 0; k < 8; ++k) a[k] = 0.f;

    for (int j = s; j < e; j += 8) {
        int j0 = j + g;
        int j1 = j + 4 + g;
        if (j0 < e) {
            int c = col[j0];
            uint4 u = *reinterpret_cast<const uint4*>(H + (size_t)c * DF + off);
            a[0] += __uint_as_float(u.x << 16);
            a[1] += __uint_as_float(u.x & 0xffff0000u);
            a[2] += __uint_as_float(u.y << 16);
            a[3] += __uint_as_float(u.y & 0xffff0000u);
            a[4] += __uint_as_float(u.z << 16);
            a[5] += __uint_as_float(u.z & 0xffff0000u);
            a[6] += __uint_as_float(u.w << 16);
            a[7] += __uint_as_float(u.w & 0xffff0000u);
        }
        if (j1 < e) {
            int c = col[j1];
            uint4 u = *reinterpret_cast<const uint4*>(H + (size_t)c * DF + off);
            a[0] += __uint_as_float(u.x << 16);
            a[1] += __uint_as_float(u.x & 0xffff0000u);
            a[2] += __uint_as_float(u.y << 16);
            a[3] += __uint_as_float(u.y & 0xffff0000u);
            a[4] += __uint_as_float(u.z << 16);
            a[5] += __uint_as_float(u.z & 0xffff0000u);
            a[6] += __uint_as_float(u.w << 16);
            a[7] += __uint_as_float(u.w & 0xffff0000u);
        }
    }

#pragma unroll
    for (int k = 0; k < 8; ++k) {
        a[k] += __shfl_xor(a[k], 16, 64);
        a[k] += __shfl_xor(a[k], 32, 64);
    }

    if (g == 0) {
        float iv = inv_deg[node];
        uint4 r;
        r.x = pack_bf16x2(a[0] * iv, a[1] * iv);
        r.y = pack_bf16x2(a[2] * iv, a[3] * iv);
        r.z = pack_bf16x2(a[4] * iv, a[5] * iv);
        r.w = pack_bf16x2(a[6] * iv, a[7] * iv);
        *reinterpret_cast<uint4*>(Agg + (size_t)node * DF + off) = r;
    }
}

// ---------------- fused GEMM: out = relu(Hb@Ws^T + Ab@Wn^T + bias) ----------------
// BM=64 rows/block, 4 waves, wave w owns output cols [32w,32w+32). K=256 (two phases).
__global__ __launch_bounds__(256) void k_gemm(const unsigned short* __restrict__ Hb,
                                              const unsigned short* __restrict__ Ab,
                                              const unsigned short* __restrict__ Wb,  // Ws | Wn (bf16)
                                              const float* __restrict__ bias,
                                              unsigned short* __restrict__ Hout,  // may alias Hb (or null)
                                              float* __restrict__ Fout,           // f32 out (or null)
                                              int n) {
    int brow = blockIdx.x * 64;
    int lane = threadIdx.x & 63;
    int wid = threadIdx.x >> 6;
    int l15 = lane & 15;
    int lk = (lane >> 4) * 8;
    int colb = wid * 32;

    f32x4 zero = {0.f, 0.f, 0.f, 0.f};
    f32x4 acc[4][2];
#pragma unroll
    for (int m = 0; m < 4; ++m) {
        acc[m][0] = zero;
        acc[m][1] = zero;
    }

#pragma unroll
    for (int ph = 0; ph < 2; ++ph) {
        const unsigned short* Ap = ph ? Ab : Hb;
        const unsigned short* Wp = Wb + ph * (DF * DF);
#pragma unroll
        for (int ks = 0; ks < 4; ++ks) {
            int kb = ks * 32 + lk;
            bf16x8 bfr0 = *reinterpret_cast<const bf16x8*>(Wp + (colb + l15) * DF + kb);
            bf16x8 bfr1 = *reinterpret_cast<const bf16x8*>(Wp + (colb + 16 + l15) * DF + kb);
#pragma unroll
            for (int m = 0; m < 4; ++m) {
                int r = brow + m * 16 + l15;
                if (r >= n) r = n - 1;
                bf16x8 afr = *reinterpret_cast<const bf16x8*>(Ap + (size_t)r * DF + kb);
                acc[m][0] = __builtin_amdgcn_mfma_f32_16x16x32_bf16(afr, bfr0, acc[m][0], 0, 0, 0);
                acc[m][1] = __builtin_amdgcn_mfma_f32_16x16x32_bf16(afr, bfr1, acc[m][1], 0, 0, 0);
            }
        }
    }

    __syncthreads();  // in-place safety: all waves' A reads complete before any store

    int rb = (lane >> 4) * 4;
#pragma unroll
    for (int q = 0; q < 2; ++q) {
        int o = colb + q * 16 + l15;
        float bv = bias[o];
#pragma unroll
        for (int m = 0; m < 4; ++m) {
#pragma unroll
            for (int j = 0; j < 4; ++j) {
                int r = brow + m * 16 + rb + j;
                if (r < n) {
                    float v = fmaxf(acc[m][q][j] + bv, 0.f);
                    if (Fout) Fout[(size_t)r * DF + o] = v;
                    else Hout[(size_t)r * DF + o] = f32_to_bf16_rne(v);
                }
            }
        }
    }
}

extern "C" void kernel_launch(void* const* d_in, const int* in_sizes, int n_in,
                              void* d_out, int out_size, void* d_ws, size_t ws_size,
                              hipStream_t stream) {
    const float* feats = (const float*)d_in[0];
    const int* src = (const int*)d_in[1];
    const int* dst = (const int*)d_in[2];
    const float* Wf[6] = {(const float*)d_in[3], (const float*)d_in[4],
                          (const float*)d_in[6], (const float*)d_in[7],
                          (const float*)d_in[9], (const float*)d_in[10]};
    const float* bias[3] = {(const float*)d_in[5], (const float*)d_in[8], (const float*)d_in[11]};

    char* ws = (char*)d_ws;
    unsigned short* h_bf = (unsigned short*)(ws);                 // 12,800,000 B
    unsigned short* agg_bf = (unsigned short*)(ws + 12800000);    // 12,800,000 B
    unsigned short* Wb = (unsigned short*)(ws + 25600000);        // 196,608 B
    int* deg = (int*)(ws + 25796608);                             // 200,000 B
    int* row_ptr = (int*)(ws + 25996608);                         // 200,004 B
    int* cursor = (int*)(ws + 26196624);                          // 200,000 B
    float* inv_deg = (float*)(ws + 26396624);                     // 200,000 B
    int* col = (int*)(ws + 26596624);                             // 3,200,000 B
    int* part = (int*)(ws + 29796624);                            // 1,024 B

    hipMemsetAsync(deg, 0, NN * sizeof(int), stream);
    k_degree<<<(NE + 255) / 256, 256, 0, stream>>>(dst, deg, NE);
    int nblk = (NN + 255) / 256;  // 196
    k_scan1<<<nblk, 256, 0, stream>>>(deg, part, NN);
    k_scan2<<<1, 256, 0, stream>>>(part, nblk, row_ptr, NN, NE);
    k_scan3<<<nblk, 256, 0, stream>>>(deg, part, row_ptr, cursor, inv_deg, NN);
    k_scatter<<<(NE + 255) / 256, 256, 0, stream>>>(src, dst, cursor, col, NE);

    k_f2b<<<(NN * DF / 4 + 255) / 256, 256, 0, stream>>>(feats, h_bf, NN * DF);
    for (int i = 0; i < 6; ++i)
        k_f2b<<<16, 256, 0, stream>>>(Wf[i], Wb + i * DF * DF, DF * DF);

    int gblk = (NN + 63) / 64;  // 782
    for (int l = 0; l < 3; ++l) {
        k_agg<<<(NN + 3) / 4, 256, 0, stream>>>(h_bf, row_ptr, col, inv_deg, agg_bf, NN);
        const unsigned short* Wl = Wb + l * 2 * DF * DF;
        if (l < 2)
            k_gemm<<<gblk, 256, 0, stream>>>(h_bf, agg_bf, Wl, bias[l], h_bf, nullptr, NN);
        else
            k_gemm<<<gblk, 256, 0, stream>>>(h_bf, agg_bf, Wl, bias[l], nullptr, (float*)d_out, NN);
    }
}